// Round 2
// baseline (133.205 us; speedup 1.0000x reference)
//
#include <hip/hip_runtime.h>

typedef float f4v __attribute__((ext_vector_type(4)));
typedef float f32x4 __attribute__((ext_vector_type(4)));
typedef __bf16 bf16x8 __attribute__((ext_vector_type(8)));
typedef unsigned short ushort8 __attribute__((ext_vector_type(8)));

static constexpr int KDIM = 2048;

// workspace layout (bytes)
static constexpr size_t OFF_XN      = 0;                                     // ushort [3][256][2048]  (3 MB)
static constexpr size_t OFF_PART    = (size_t)3 * 256 * 2048 * 2;            // float  [768][256][4]   (3 MB)
static constexpr size_t OFF_DOTT    = OFF_PART + (size_t)768 * 256 * 16;     // float  [768]
static constexpr size_t OFF_ROWLOSS = OFF_DOTT + 768 * 4;                    // float  [768]

__device__ __forceinline__ unsigned short f2bf(float x) {
  union { float f; unsigned u; } c; c.f = x;
  unsigned r = c.u + 0x7fffu + ((c.u >> 16) & 1u);   // RNE
  return (unsigned short)(r >> 16);
}

// ---------------- kernel 1: row-normalize inputs -> bf16 ----------------
__global__ __launch_bounds__(256) void k_normalize(
    const float* __restrict__ x0, const float* __restrict__ x1, const float* __restrict__ x2,
    unsigned short* __restrict__ xn)
{
  int bid = blockIdx.x;            // 0..767 : branch*256 + row
  int branch = bid >> 8;
  int row = bid & 255;
  const float* src = (branch == 0 ? x0 : (branch == 1 ? x1 : x2)) + (size_t)row * KDIM;
  int tid = threadIdx.x;
  f4v a = *(const f4v*)(src + tid * 8);
  f4v b = *(const f4v*)(src + tid * 8 + 4);
  float s = a[0]*a[0] + a[1]*a[1] + a[2]*a[2] + a[3]*a[3]
          + b[0]*b[0] + b[1]*b[1] + b[2]*b[2] + b[3]*b[3];
  #pragma unroll
  for (int m = 1; m < 64; m <<= 1) s += __shfl_xor(s, m);
  __shared__ float ls[4];
  if ((tid & 63) == 0) ls[tid >> 6] = s;
  __syncthreads();
  float total = ls[0] + ls[1] + ls[2] + ls[3];
  float inv = 1.0f / fmaxf(sqrtf(total), 1e-12f);
  ushort8 u;
  #pragma unroll
  for (int e = 0; e < 4; ++e) u[e]     = f2bf(a[e] * inv);
  #pragma unroll
  for (int e = 0; e < 4; ++e) u[4 + e] = f2bf(b[e] * inv);
  *(ushort8*)(xn + (size_t)bid * KDIM + tid * 8) = u;
}

// ---------------- kernel 2: fused GEMM + per-tile reductions ----------------
// BM=256 (all rows, so each feature row is streamed from HBM exactly once),
// BN=32, BK=64. 4 waves M-stacked, each computing a 64x32 tile.
// A: direct global->reg (bf16, L2-resident). B: nontemporal f32 stream ->
// regs -> bf16 -> LDS (double-buffered, shared by the 4 waves).
__global__ __launch_bounds__(256, 3) void k_gemm_fused(
    const unsigned short* __restrict__ xn,
    const float* __restrict__ f0, const float* __restrict__ f1, const float* __restrict__ f2,
    const int* __restrict__ targets,
    float* __restrict__ part, float* __restrict__ dotT)
{
  __shared__ unsigned short lB[2 * 32 * 64];   // 2 x 4 KiB, XOR-swizzled 16B chunks

  int bid = blockIdx.x;
  int swz = (bid & 7) * 96 + (bid >> 3);       // XCD swizzle, 768 % 8 == 0 -> bijective
  int branch = swz >> 8;
  int ntile = swz & 255;                        // 256 n-tiles of 32 cols

  const unsigned short* A = xn + (size_t)branch * (256 * 2048);
  const float* F = (branch == 0 ? f0 : (branch == 1 ? f1 : f2)) + (size_t)ntile * 32 * 2048;

  int tid = threadIdx.x;
  int wave = tid >> 6;
  int lane = tid & 63;
  int rcol0 = lane & 15;

  // B prefetch: thread covers col = tid>>3, k-chunk = tid&7 (8 f32)
  const float* bSrc = F + (size_t)(tid >> 3) * 2048 + (tid & 7) * 8;
  int wcol = tid >> 3;
  int wByte = wcol * 128 + (((tid & 7) ^ (wcol & 7)) << 4);

  // A per-lane fragment bases (row = wave*64 + i*16 + (lane&15), k-lane-offset = (lane>>4)*8)
  const unsigned short* aBase = A + (size_t)(wave * 64 + rcol0) * 2048 + (lane >> 4) * 8;
  const unsigned short* aP0 = aBase;
  const unsigned short* aP1 = aBase + 16 * 2048;
  const unsigned short* aP2 = aBase + 32 * 2048;
  const unsigned short* aP3 = aBase + 48 * 2048;

  f32x4 acc[4][2];
  #pragma unroll
  for (int i = 0; i < 4; ++i)
    #pragma unroll
    for (int j = 0; j < 2; ++j)
      #pragma unroll
      for (int q = 0; q < 4; ++q) acc[i][j][q] = 0.0f;

  f4v bs0, bs1;

#define LOAD_B(kt) do { \
    bs0 = __builtin_nontemporal_load((const f4v*)(bSrc + (kt) * 64)); \
    bs1 = __builtin_nontemporal_load((const f4v*)(bSrc + (kt) * 64 + 4)); \
  } while (0)

#define WRITE_B(bufsel) do { \
    ushort8 u; \
    _Pragma("unroll") for (int e = 0; e < 4; ++e) u[e]     = f2bf(bs0[e]); \
    _Pragma("unroll") for (int e = 0; e < 4; ++e) u[4 + e] = f2bf(bs1[e]); \
    *(ushort8*)((char*)lB + (bufsel) * 4096 + wByte) = u; \
  } while (0)

#define COMPUTE(cur, kt) do { \
    const char* rb = (const char*)lB + (cur) * 4096; \
    _Pragma("unroll") for (int ks = 0; ks < 2; ++ks) { \
      int chunk = (((ks * 4 + (lane >> 4)) ^ (rcol0 & 7)) << 4); \
      bf16x8 bj0 = *(const bf16x8*)(rb + rcol0 * 128 + chunk); \
      bf16x8 bj1 = *(const bf16x8*)(rb + (rcol0 + 16) * 128 + chunk); \
      bf16x8 a0 = *(const bf16x8*)(aP0 + (kt) * 64 + ks * 32); \
      bf16x8 a1 = *(const bf16x8*)(aP1 + (kt) * 64 + ks * 32); \
      bf16x8 a2 = *(const bf16x8*)(aP2 + (kt) * 64 + ks * 32); \
      bf16x8 a3 = *(const bf16x8*)(aP3 + (kt) * 64 + ks * 32); \
      acc[0][0] = __builtin_amdgcn_mfma_f32_16x16x32_bf16(a0, bj0, acc[0][0], 0, 0, 0); \
      acc[0][1] = __builtin_amdgcn_mfma_f32_16x16x32_bf16(a0, bj1, acc[0][1], 0, 0, 0); \
      acc[1][0] = __builtin_amdgcn_mfma_f32_16x16x32_bf16(a1, bj0, acc[1][0], 0, 0, 0); \
      acc[1][1] = __builtin_amdgcn_mfma_f32_16x16x32_bf16(a1, bj1, acc[1][1], 0, 0, 0); \
      acc[2][0] = __builtin_amdgcn_mfma_f32_16x16x32_bf16(a2, bj0, acc[2][0], 0, 0, 0); \
      acc[2][1] = __builtin_amdgcn_mfma_f32_16x16x32_bf16(a2, bj1, acc[2][1], 0, 0, 0); \
      acc[3][0] = __builtin_amdgcn_mfma_f32_16x16x32_bf16(a3, bj0, acc[3][0], 0, 0, 0); \
      acc[3][1] = __builtin_amdgcn_mfma_f32_16x16x32_bf16(a3, bj1, acc[3][1], 0, 0, 0); \
    } \
  } while (0)

  // prologue: stage tile 0, issue loads for tile 1
  LOAD_B(0);
  WRITE_B(0);
  LOAD_B(1);
  __syncthreads();

  // steady state: write B(t+1), issue loads B(t+2), compute tile t
  for (int t = 0; t < 30; ++t) {
    WRITE_B((t + 1) & 1);
    LOAD_B(t + 2);
    COMPUTE(t & 1, t);
    __syncthreads();
  }
  WRITE_B(1);          // tile 31 -> buf1
  COMPUTE(0, 30);
  __syncthreads();
  COMPUTE(1, 31);

#undef LOAD_B
#undef WRITE_B
#undef COMPUTE

  // fused epilogue: per-row partials over this 32-col tile.
  // p1 = sum exp(20d-20), Z1 = sum exp(D-2), Z2 = sum exp(2(D-2)), Z3 = sum exp(3(D-2))
  // where D = sqrt(max(2-2d,0)).  C/D layout: col = lane&15, row = (lane>>4)*4 + q.
  int tbase = branch * 256;
  #pragma unroll
  for (int i = 0; i < 4; ++i) {
    #pragma unroll
    for (int q = 0; q < 4; ++q) {
      int row = wave * 64 + i * 16 + ((lane >> 4) << 2) + q;
      int tgt = targets[row];
      float s1 = 0.f, s2 = 0.f, s3 = 0.f, s4 = 0.f;
      #pragma unroll
      for (int j = 0; j < 2; ++j) {
        float d = acc[i][j][q];
        float e1 = __expf(fmaf(20.0f, d, -20.0f));
        float Dv = sqrtf(fmaxf(2.0f - 2.0f * d, 0.0f));
        float e2 = __expf(Dv - 2.0f);
        s1 += e1; s2 += e2;
        float t2 = e2 * e2;
        s3 += t2; s4 += t2 * e2;
        int col = ntile * 32 + j * 16 + rcol0;
        if (col == tgt) dotT[tbase + row] = d;   // exactly one writer per row globally
      }
      #pragma unroll
      for (int m = 1; m < 16; m <<= 1) {         // reduce across the 16 lanes sharing this row
        s1 += __shfl_xor(s1, m);
        s2 += __shfl_xor(s2, m);
        s3 += __shfl_xor(s3, m);
        s4 += __shfl_xor(s4, m);
      }
      if (rcol0 == 0) {
        f32x4 p; p[0] = s1; p[1] = s2; p[2] = s3; p[3] = s4;
        *(f32x4*)(part + ((size_t)(tbase + row) * 256 + ntile) * 4) = p;
      }
    }
  }
}

// ---------------- kernel 3: combine 256 tile-partials per row -> row loss ----------------
__global__ __launch_bounds__(256) void k_combine(
    const float* __restrict__ part, const float* __restrict__ dotT, float* __restrict__ rowloss)
{
  int row = blockIdx.x;    // 0..767
  int tid = threadIdx.x;   // 256
  f4v p = *(const f4v*)(part + ((size_t)row * 256 + tid) * 4);
  float a0 = p[0], a1 = p[1], a2 = p[2], a3 = p[3];
  #pragma unroll
  for (int m = 1; m < 64; m <<= 1) {
    a0 += __shfl_xor(a0, m); a1 += __shfl_xor(a1, m);
    a2 += __shfl_xor(a2, m); a3 += __shfl_xor(a3, m);
  }
  __shared__ float ls[4][4];
  if ((tid & 63) == 0) {
    int w = tid >> 6;
    ls[0][w] = a0; ls[1][w] = a1; ls[2][w] = a2; ls[3][w] = a3;
  }
  __syncthreads();
  if (tid == 0) {
    float p1 = ls[0][0] + ls[0][1] + ls[0][2] + ls[0][3];
    float Z1 = ls[1][0] + ls[1][1] + ls[1][2] + ls[1][3];
    float Z2 = ls[2][0] + ls[2][1] + ls[2][2] + ls[2][3];
    float Z3 = ls[3][0] + ls[3][1] + ls[3][2] + ls[3][3];
    float dt = dotT[row];
    // CE1 = logsumexp(20*dot) - 20*dot_t   (fixed shift 20 is exact: 20d-20 <= 0)
    float CE1 = 20.0f + logf(p1) - 20.0f * dt;
    // CE2 = log(sum_n exp(S_n)) - S_t ;  sum_n exp(S_n) = N + 1 + Z2/(2 Z1^2) + Z3/(6 Z1^3)
    float Dt = sqrtf(fmaxf(2.0f - 2.0f * dt, 0.0f));
    float St = __expf(Dt - 2.0f) / Z1;
    float sES = 8193.0f + Z2 / (2.0f * Z1 * Z1) + Z3 / (6.0f * Z1 * Z1 * Z1);
    float CE2 = logf(sES) - St;
    rowloss[row] = (CE1 + CE2) * (0.5f / 256.0f);
  }
}

// ---------------- kernel 4: final sum ----------------
__global__ __launch_bounds__(256) void k_final(const float* __restrict__ rowloss, float* __restrict__ out)
{
  int tid = threadIdx.x;
  float v = rowloss[tid] + rowloss[tid + 256] + rowloss[tid + 512];
  #pragma unroll
  for (int m = 1; m < 64; m <<= 1) v += __shfl_xor(v, m);
  __shared__ float ls[4];
  if ((tid & 63) == 0) ls[tid >> 6] = v;
  __syncthreads();
  if (tid == 0) out[0] = ls[0] + ls[1] + ls[2] + ls[3];
}

extern "C" void kernel_launch(void* const* d_in, const int* in_sizes, int n_in,
                              void* d_out, int out_size, void* d_ws, size_t ws_size,
                              hipStream_t stream) {
  const float* in0 = (const float*)d_in[0];
  const float* in1 = (const float*)d_in[1];
  const float* in2 = (const float*)d_in[2];
  const int* targets = (const int*)d_in[3];
  // d_in[4] = epoch (unused by the loss)
  const float* f0 = (const float*)d_in[5];
  const float* f1 = (const float*)d_in[6];
  const float* f2 = (const float*)d_in[7];

  char* ws = (char*)d_ws;
  unsigned short* xn = (unsigned short*)(ws + OFF_XN);
  float* part    = (float*)(ws + OFF_PART);
  float* dotT    = (float*)(ws + OFF_DOTT);
  float* rowloss = (float*)(ws + OFF_ROWLOSS);
  float* out = (float*)d_out;

  k_normalize<<<768, 256, 0, stream>>>(in0, in1, in2, xn);
  k_gemm_fused<<<768, 256, 0, stream>>>(xn, f0, f1, f2, targets, part, dotT);
  k_combine<<<768, 256, 0, stream>>>(part, dotT, rowloss);
  k_final<<<1, 256, 0, stream>>>(rowloss, out);
}

// Round 3
// 119.037 us; speedup vs baseline: 1.1190x; 1.1190x over previous
//
#include <hip/hip_runtime.h>

typedef float f4v __attribute__((ext_vector_type(4)));
typedef float f32x4 __attribute__((ext_vector_type(4)));
typedef __bf16 bf16x8 __attribute__((ext_vector_type(8)));
typedef unsigned short ushort8 __attribute__((ext_vector_type(8)));

static constexpr int KDIM = 2048;

// workspace layout (bytes)
static constexpr size_t OFF_XN      = 0;                                     // ushort [3][256][2048]  (3 MB)
static constexpr size_t OFF_PART    = (size_t)3 * 256 * 2048 * 2;            // float  [768][256][4]   (3 MB)
static constexpr size_t OFF_DOTT    = OFF_PART + (size_t)768 * 256 * 16;     // float  [768]
static constexpr size_t OFF_ROWLOSS = OFF_DOTT + 768 * 4;                    // float  [768]

__device__ __forceinline__ unsigned short f2bf(float x) {
  union { float f; unsigned u; } c; c.f = x;
  unsigned r = c.u + 0x7fffu + ((c.u >> 16) & 1u);   // RNE
  return (unsigned short)(r >> 16);
}

__device__ __forceinline__ void gload_lds16(const void* g, void* l) {
  __builtin_amdgcn_global_load_lds((const __attribute__((address_space(1))) void*)g,
                                   (__attribute__((address_space(3))) void*)l,
                                   16, 0, 0);
}

__device__ __forceinline__ bf16x8 cvt8(f4v lo, f4v hi) {
  bf16x8 r;
  r[0] = (__bf16)lo[0]; r[1] = (__bf16)lo[1]; r[2] = (__bf16)lo[2]; r[3] = (__bf16)lo[3];
  r[4] = (__bf16)hi[0]; r[5] = (__bf16)hi[1]; r[6] = (__bf16)hi[2]; r[7] = (__bf16)hi[3];
  return r;
}

// ---------------- kernel 1: row-normalize inputs -> bf16 ----------------
__global__ __launch_bounds__(256) void k_normalize(
    const float* __restrict__ x0, const float* __restrict__ x1, const float* __restrict__ x2,
    unsigned short* __restrict__ xn)
{
  int bid = blockIdx.x;            // 0..767 : branch*256 + row
  int branch = bid >> 8;
  int row = bid & 255;
  const float* src = (branch == 0 ? x0 : (branch == 1 ? x1 : x2)) + (size_t)row * KDIM;
  int tid = threadIdx.x;
  f4v a = *(const f4v*)(src + tid * 8);
  f4v b = *(const f4v*)(src + tid * 8 + 4);
  float s = a[0]*a[0] + a[1]*a[1] + a[2]*a[2] + a[3]*a[3]
          + b[0]*b[0] + b[1]*b[1] + b[2]*b[2] + b[3]*b[3];
  #pragma unroll
  for (int m = 1; m < 64; m <<= 1) s += __shfl_xor(s, m);
  __shared__ float ls[4];
  if ((tid & 63) == 0) ls[tid >> 6] = s;
  __syncthreads();
  float total = ls[0] + ls[1] + ls[2] + ls[3];
  float inv = 1.0f / fmaxf(sqrtf(total), 1e-12f);
  ushort8 u;
  #pragma unroll
  for (int e = 0; e < 4; ++e) u[e]     = f2bf(a[e] * inv);
  #pragma unroll
  for (int e = 0; e < 4; ++e) u[4 + e] = f2bf(b[e] * inv);
  *(ushort8*)(xn + (size_t)bid * KDIM + tid * 8) = u;
}

// ---------------- kernel 2: fused GEMM + per-tile reductions ----------------
// BM=256 (B streamed from HBM exactly once), BN=32, BK=64, grid 768 = 3 blocks/CU.
// A: register double-buffer, prefetched 1 tile ahead (L2-resident xn).
// B: 3-deep LDS ring via global_load_lds (f32), staged 2 tiles ahead,
//    counted vmcnt (never drained to 0 in the loop), raw s_barrier.
__global__ __launch_bounds__(256, 3) void k_gemm_fused(
    const unsigned short* __restrict__ xn,
    const float* __restrict__ f0, const float* __restrict__ f1, const float* __restrict__ f2,
    const int* __restrict__ targets,
    float* __restrict__ part, float* __restrict__ dotT)
{
  __shared__ float lB[3 * 2048];   // 3 ring slots x 8 KiB (32 F-rows x 64 k f32), swizzled

  int bid = blockIdx.x;
  int swz = (bid & 7) * 96 + (bid >> 3);       // XCD swizzle, 768 % 8 == 0 -> bijective
  int branch = swz >> 8;
  int ntile = swz & 255;                        // 256 n-tiles of 32 cols

  const unsigned short* A = xn + (size_t)branch * (256 * 2048);
  const float* F = (branch == 0 ? f0 : (branch == 1 ? f1 : f2)) + (size_t)ntile * 32 * 2048;

  int tid = threadIdx.x;
  int wave = tid >> 6;
  int lane = tid & 63;
  int rcol0 = lane & 15;
  int klane = lane >> 4;

  // ---- B staging addressing: chunk c in [0,512): col = c>>4, chunk-in-col = c&15,
  // source pre-swizzled (gc = cic ^ (col&7)) so linear LDS dest == swizzled layout.
  int c0 = tid,       col0 = c0 >> 4, g0 = (c0 & 15) ^ (col0 & 7);
  int c1 = 256 + tid, col1 = c1 >> 4, g1 = (c1 & 15) ^ (col1 & 7);
  const float* bs0 = F + (size_t)col0 * KDIM + g0 * 4;
  const float* bs1 = F + (size_t)col1 * KDIM + g1 * 4;
  char* ldst0 = (char*)lB + (0   + wave * 64) * 16;   // wave-uniform dest bases
  char* ldst1 = (char*)lB + (256 + wave * 64) * 16;

#define STAGE_B(kt, slotByte) do { \
    gload_lds16(bs0 + (kt) * 64, ldst0 + (slotByte)); \
    gload_lds16(bs1 + (kt) * 64, ldst1 + (slotByte)); \
  } while (0)

  // ---- A fragment addressing (row = wave*64 + i*16 + rcol0, k-off = klane*8)
  const unsigned short* aBase = A + (size_t)(wave * 64 + rcol0) * KDIM + klane * 8;

  bf16x8 aA[4][2], aB[4][2];

#define LOAD_A(kt, dst) do { \
    _Pragma("unroll") for (int i = 0; i < 4; ++i) { \
      dst[i][0] = *(const bf16x8*)(aBase + (size_t)i * 16 * KDIM + (kt) * 64); \
      dst[i][1] = *(const bf16x8*)(aBase + (size_t)i * 16 * KDIM + (kt) * 64 + 32); \
    } \
  } while (0)

  f32x4 acc[4][2];
  #pragma unroll
  for (int i = 0; i < 4; ++i)
    #pragma unroll
    for (int j = 0; j < 2; ++j)
      #pragma unroll
      for (int q = 0; q < 4; ++q) acc[i][j][q] = 0.0f;

#define COMPUTE(slotByte, aX) do { \
    const char* rb = (const char*)lB + (slotByte); \
    const char* r0 = rb + rcol0 * 256; \
    const char* r1 = rb + (rcol0 + 16) * 256; \
    int sx = rcol0 & 7; \
    _Pragma("unroll") for (int ks = 0; ks < 2; ++ks) { \
      int cA = ks * 8 + klane * 2; \
      f4v p00 = *(const f4v*)(r0 + (((cA)     ^ sx) << 4)); \
      f4v p01 = *(const f4v*)(r0 + (((cA + 1) ^ sx) << 4)); \
      f4v p10 = *(const f4v*)(r1 + (((cA)     ^ sx) << 4)); \
      f4v p11 = *(const f4v*)(r1 + (((cA + 1) ^ sx) << 4)); \
      bf16x8 b0 = cvt8(p00, p01); \
      bf16x8 b1 = cvt8(p10, p11); \
      acc[0][0] = __builtin_amdgcn_mfma_f32_16x16x32_bf16(aX[0][ks], b0, acc[0][0], 0, 0, 0); \
      acc[0][1] = __builtin_amdgcn_mfma_f32_16x16x32_bf16(aX[0][ks], b1, acc[0][1], 0, 0, 0); \
      acc[1][0] = __builtin_amdgcn_mfma_f32_16x16x32_bf16(aX[1][ks], b0, acc[1][0], 0, 0, 0); \
      acc[1][1] = __builtin_amdgcn_mfma_f32_16x16x32_bf16(aX[1][ks], b1, acc[1][1], 0, 0, 0); \
      acc[2][0] = __builtin_amdgcn_mfma_f32_16x16x32_bf16(aX[2][ks], b0, acc[2][0], 0, 0, 0); \
      acc[2][1] = __builtin_amdgcn_mfma_f32_16x16x32_bf16(aX[2][ks], b1, acc[2][1], 0, 0, 0); \
      acc[3][0] = __builtin_amdgcn_mfma_f32_16x16x32_bf16(aX[3][ks], b0, acc[3][0], 0, 0, 0); \
      acc[3][1] = __builtin_amdgcn_mfma_f32_16x16x32_bf16(aX[3][ks], b1, acc[3][1], 0, 0, 0); \
    } \
  } while (0)

#define WAIT_BARRIER(n) do { \
    asm volatile("s_waitcnt vmcnt(" #n ")" ::: "memory"); \
    __builtin_amdgcn_s_barrier(); \
    asm volatile("" ::: "memory"); \
  } while (0)

  // prologue — issue order must match steady state: B(t), A(t), B(t+1), A(t+1)
  STAGE_B(0, 0);
  LOAD_A(0, aA);
  STAGE_B(1, 8192);

  int slotC = 0;       // byte offset of slot holding tile t
  int slotS = 16384;   // byte offset of slot to stage tile t+2 into

  for (int t = 0; t < 30; t += 2) {
    // even tile t: compute aA
    LOAD_A(t + 1, aB);
    WAIT_BARRIER(10);                 // leaves B(t+1)x2 + A(t+1)x8 in flight
    STAGE_B(t + 2, slotS);            // safe: all waves past compute(t-1)
    COMPUTE(slotC, aA);
    slotC = (slotC == 16384) ? 0 : slotC + 8192;
    slotS = (slotS == 16384) ? 0 : slotS + 8192;
    // odd tile t+1: compute aB
    LOAD_A(t + 2, aA);
    WAIT_BARRIER(10);
    STAGE_B(t + 3, slotS);
    COMPUTE(slotC, aB);
    slotC = (slotC == 16384) ? 0 : slotC + 8192;
    slotS = (slotS == 16384) ? 0 : slotS + 8192;
  }
  // tile 30
  LOAD_A(31, aB);
  WAIT_BARRIER(10);
  COMPUTE(slotC, aA);
  slotC = (slotC == 16384) ? 0 : slotC + 8192;
  // tile 31
  WAIT_BARRIER(0);
  COMPUTE(slotC, aB);

#undef STAGE_B
#undef LOAD_A
#undef COMPUTE
#undef WAIT_BARRIER

  // fused epilogue: per-row partials over this 32-col tile.
  // p1 = sum exp(20d-20), Z1 = sum exp(D-2), Z2 = sum exp(2(D-2)), Z3 = sum exp(3(D-2))
  // where D = sqrt(max(2-2d,0)).  C/D layout: col = lane&15, row = (lane>>4)*4 + q.
  int tbase = branch * 256;
  #pragma unroll
  for (int i = 0; i < 4; ++i) {
    #pragma unroll
    for (int q = 0; q < 4; ++q) {
      int row = wave * 64 + i * 16 + (klane << 2) + q;
      int tgt = targets[row];
      float s1 = 0.f, s2 = 0.f, s3 = 0.f, s4 = 0.f;
      #pragma unroll
      for (int j = 0; j < 2; ++j) {
        float d = acc[i][j][q];
        float e1 = __expf(fmaf(20.0f, d, -20.0f));
        float Dv = sqrtf(fmaxf(2.0f - 2.0f * d, 0.0f));
        float e2 = __expf(Dv - 2.0f);
        s1 += e1; s2 += e2;
        float t2 = e2 * e2;
        s3 += t2; s4 += t2 * e2;
        int col = ntile * 32 + j * 16 + rcol0;
        if (col == tgt) dotT[tbase + row] = d;   // exactly one writer per row globally
      }
      #pragma unroll
      for (int m = 1; m < 16; m <<= 1) {         // reduce across the 16 lanes sharing this row
        s1 += __shfl_xor(s1, m);
        s2 += __shfl_xor(s2, m);
        s3 += __shfl_xor(s3, m);
        s4 += __shfl_xor(s4, m);
      }
      if (rcol0 == 0) {
        f32x4 p; p[0] = s1; p[1] = s2; p[2] = s3; p[3] = s4;
        *(f32x4*)(part + ((size_t)(tbase + row) * 256 + ntile) * 4) = p;
      }
    }
  }
}

// ---------------- kernel 3: combine 256 tile-partials per row -> row loss ----------------
__global__ __launch_bounds__(256) void k_combine(
    const float* __restrict__ part, const float* __restrict__ dotT, float* __restrict__ rowloss)
{
  int row = blockIdx.x;    // 0..767
  int tid = threadIdx.x;   // 256
  f4v p = *(const f4v*)(part + ((size_t)row * 256 + tid) * 4);
  float a0 = p[0], a1 = p[1], a2 = p[2], a3 = p[3];
  #pragma unroll
  for (int m = 1; m < 64; m <<= 1) {
    a0 += __shfl_xor(a0, m); a1 += __shfl_xor(a1, m);
    a2 += __shfl_xor(a2, m); a3 += __shfl_xor(a3, m);
  }
  __shared__ float ls[4][4];
  if ((tid & 63) == 0) {
    int w = tid >> 6;
    ls[0][w] = a0; ls[1][w] = a1; ls[2][w] = a2; ls[3][w] = a3;
  }
  __syncthreads();
  if (tid == 0) {
    float p1 = ls[0][0] + ls[0][1] + ls[0][2] + ls[0][3];
    float Z1 = ls[1][0] + ls[1][1] + ls[1][2] + ls[1][3];
    float Z2 = ls[2][0] + ls[2][1] + ls[2][2] + ls[2][3];
    float Z3 = ls[3][0] + ls[3][1] + ls[3][2] + ls[3][3];
    float dt = dotT[row];
    // CE1 = logsumexp(20*dot) - 20*dot_t   (fixed shift 20 is exact: 20d-20 <= 0)
    float CE1 = 20.0f + logf(p1) - 20.0f * dt;
    // CE2 = log(sum_n exp(S_n)) - S_t ;  sum_n exp(S_n) = N + 1 + Z2/(2 Z1^2) + Z3/(6 Z1^3)
    float Dt = sqrtf(fmaxf(2.0f - 2.0f * dt, 0.0f));
    float St = __expf(Dt - 2.0f) / Z1;
    float sES = 8193.0f + Z2 / (2.0f * Z1 * Z1) + Z3 / (6.0f * Z1 * Z1 * Z1);
    float CE2 = logf(sES) - St;
    rowloss[row] = (CE1 + CE2) * (0.5f / 256.0f);
  }
}

// ---------------- kernel 4: final sum ----------------
__global__ __launch_bounds__(256) void k_final(const float* __restrict__ rowloss, float* __restrict__ out)
{
  int tid = threadIdx.x;
  float v = rowloss[tid] + rowloss[tid + 256] + rowloss[tid + 512];
  #pragma unroll
  for (int m = 1; m < 64; m <<= 1) v += __shfl_xor(v, m);
  __shared__ float ls[4];
  if ((tid & 63) == 0) ls[tid >> 6] = v;
  __syncthreads();
  if (tid == 0) out[0] = ls[0] + ls[1] + ls[2] + ls[3];
}

extern "C" void kernel_launch(void* const* d_in, const int* in_sizes, int n_in,
                              void* d_out, int out_size, void* d_ws, size_t ws_size,
                              hipStream_t stream) {
  const float* in0 = (const float*)d_in[0];
  const float* in1 = (const float*)d_in[1];
  const float* in2 = (const float*)d_in[2];
  const int* targets = (const int*)d_in[3];
  // d_in[4] = epoch (unused by the loss)
  const float* f0 = (const float*)d_in[5];
  const float* f1 = (const float*)d_in[6];
  const float* f2 = (const float*)d_in[7];

  char* ws = (char*)d_ws;
  unsigned short* xn = (unsigned short*)(ws + OFF_XN);
  float* part    = (float*)(ws + OFF_PART);
  float* dotT    = (float*)(ws + OFF_DOTT);
  float* rowloss = (float*)(ws + OFF_ROWLOSS);
  float* out = (float*)d_out;

  k_normalize<<<768, 256, 0, stream>>>(in0, in1, in2, xn);
  k_gemm_fused<<<768, 256, 0, stream>>>(xn, f0, f1, f2, targets, part, dotT);
  k_combine<<<768, 256, 0, stream>>>(part, dotT, rowloss);
  k_final<<<1, 256, 0, stream>>>(rowloss, out);
}

// Round 5
// 70.756 us; speedup vs baseline: 1.8826x; 1.6824x over previous
//
#include <hip/hip_runtime.h>

typedef float f4v __attribute__((ext_vector_type(4)));
typedef float f32x4 __attribute__((ext_vector_type(4)));
typedef __bf16 bf16x8 __attribute__((ext_vector_type(8)));
typedef unsigned short ushort8 __attribute__((ext_vector_type(8)));
typedef unsigned short us4v __attribute__((ext_vector_type(4)));

static constexpr int KDIM = 2048;

// workspace layout (bytes)
static constexpr size_t OFF_XN      = 0;                                     // ushort [3][256][2048]  (3 MB)
static constexpr size_t OFF_PART    = (size_t)3 * 256 * 2048 * 2;            // float  [768][256][4]   (3 MB)
static constexpr size_t OFF_DOTT    = OFF_PART + (size_t)768 * 256 * 16;     // float  [768]
static constexpr size_t OFF_ROWLOSS = OFF_DOTT + 768 * 4;                    // float  [768]

__device__ __forceinline__ unsigned short f2bf(float x) {
  union { float f; unsigned u; } c; c.f = x;
  unsigned r = c.u + 0x7fffu + ((c.u >> 16) & 1u);   // RNE
  return (unsigned short)(r >> 16);
}

__device__ __forceinline__ void gload_lds16(const void* g, void* l) {
  __builtin_amdgcn_global_load_lds((const __attribute__((address_space(1))) void*)g,
                                   (__attribute__((address_space(3))) void*)l,
                                   16, 0, 0);
}

// ---------------- kernel 1: row-normalize inputs -> bf16 ----------------
__global__ __launch_bounds__(256) void k_normalize(
    const float* __restrict__ x0, const float* __restrict__ x1, const float* __restrict__ x2,
    unsigned short* __restrict__ xn)
{
  int bid = blockIdx.x;            // 0..767 : branch*256 + row
  int branch = bid >> 8;
  int row = bid & 255;
  const float* src = (branch == 0 ? x0 : (branch == 1 ? x1 : x2)) + (size_t)row * KDIM;
  int tid = threadIdx.x;
  f4v a = *(const f4v*)(src + tid * 8);
  f4v b = *(const f4v*)(src + tid * 8 + 4);
  float s = a[0]*a[0] + a[1]*a[1] + a[2]*a[2] + a[3]*a[3]
          + b[0]*b[0] + b[1]*b[1] + b[2]*b[2] + b[3]*b[3];
  #pragma unroll
  for (int m = 1; m < 64; m <<= 1) s += __shfl_xor(s, m);
  __shared__ float ls[4];
  if ((tid & 63) == 0) ls[tid >> 6] = s;
  __syncthreads();
  float total = ls[0] + ls[1] + ls[2] + ls[3];
  float inv = 1.0f / fmaxf(sqrtf(total), 1e-12f);
  ushort8 u;
  #pragma unroll
  for (int e = 0; e < 4; ++e) u[e]     = f2bf(a[e] * inv);
  #pragma unroll
  for (int e = 0; e < 4; ++e) u[4 + e] = f2bf(b[e] * inv);
  *(ushort8*)(xn + (size_t)bid * KDIM + tid * 8) = u;
}

// ---------------- kernel 2: fused GEMM + per-tile reductions ----------------
// BM=128, BN=64, BK=64. Grid = 3 branches x 2 mtiles x 128 ntiles = 768 = 3 blocks/CU.
// 4 waves (2M x 2N), each computing 64x32.
// A (bf16 xn): global_load_lds, per-lane pre-swizzled source, linear LDS dest.
// B (f32 features): global->reg (coalesced 256B runs) -> cvt bf16 -> swizzled ds_write.
// Plain __syncthreads() per K-tile (m97 structure).
__global__ __launch_bounds__(256, 3) void k_gemm_fused(
    const unsigned short* __restrict__ xn,
    const float* __restrict__ f0, const float* __restrict__ f1, const float* __restrict__ f2,
    const int* __restrict__ targets,
    float* __restrict__ part, float* __restrict__ dotT)
{
  // per buffer: A = 128 rows x 128B = 16 KiB, B = 64 cols x 128B = 8 KiB
  __shared__ char lds[2 * 24576];

  int bid = blockIdx.x;
  int swz = (bid & 7) * 96 + (bid >> 3);   // XCD-aware, 768 % 8 == 0 -> bijective
  int branch = swz >> 8;
  int ntile = (swz & 255) >> 1;            // 128 n-tiles of 64 cols
  int mtile = swz & 1;                     // 2 m-tiles of 128 rows (siblings adjacent -> L2 share B)

  const unsigned short* A = xn + ((size_t)branch * 256 + (size_t)mtile * 128) * KDIM;
  const float* F = (branch == 0 ? f0 : (branch == 1 ? f1 : f2)) + (size_t)ntile * 64 * KDIM;

  int tid = threadIdx.x;
  int wave = tid >> 6;
  int lane = tid & 63;
  int rcol0 = lane & 15;
  int klane = lane >> 4;
  int wr = wave >> 1;    // M quadrant (0..1)
  int wc = wave & 1;     // N quadrant (0..1)

  // ---- A staging: 4 x gload_lds(16B) per thread. c = g*256+tid:
  // row = c>>3, physical chunk = c&7, logical chunk = (c&7)^(row&7).
  const unsigned short* aSrc = A + (size_t)(tid >> 3) * KDIM
                             + (((tid & 7) ^ ((tid >> 3) & 7)) << 3);
  char* aDst = lds + (wave * 64) * 16;     // wave-uniform base; +g*4096; +buf*24576

#define STAGE_A(kt, buf) do { \
    _Pragma("unroll") for (int g = 0; g < 4; ++g) \
      gload_lds16(aSrc + (size_t)g * 32 * KDIM + (kt) * 64, \
                  aDst + (buf) * 24576 + g * 4096); \
  } while (0)

  // ---- B global loads: c = g*256+tid: row = g*16 + (tid>>4), 16B chunk = tid&15.
  const float* bSrc = F + (size_t)(tid >> 4) * KDIM + (tid & 15) * 4;
  f4v bg0, bg1, bg2, bg3;

#define LOADB_G(kt) do { \
    bg0 = *(const f4v*)(bSrc + (kt) * 64); \
    bg1 = *(const f4v*)(bSrc + 16 * KDIM + (kt) * 64); \
    bg2 = *(const f4v*)(bSrc + 32 * KDIM + (kt) * 64); \
    bg3 = *(const f4v*)(bSrc + 48 * KDIM + (kt) * 64); \
  } while (0)

  // ---- B LDS write: row = g*16+(tid>>4); 8B-half h = tid&1; logical 16B chunk l = (tid&15)>>1
  // byte = 16384(A) + row*128 + ((l ^ (row&7))<<4) + h*8
  int bOff = 16384 + (tid >> 4) * 128
           + (((((tid & 15) >> 1)) ^ ((tid >> 4) & 7)) << 4) + (tid & 1) * 8;

#define WRITE_B(buf) do { \
    us4v v0, v1, v2, v3; \
    _Pragma("unroll") for (int e = 0; e < 4; ++e) { \
      v0[e] = f2bf(bg0[e]); v1[e] = f2bf(bg1[e]); \
      v2[e] = f2bf(bg2[e]); v3[e] = f2bf(bg3[e]); \
    } \
    char* wb = lds + (buf) * 24576 + bOff; \
    *(us4v*)(wb)          = v0; \
    *(us4v*)(wb + 2048)   = v1; \
    *(us4v*)(wb + 4096)   = v2; \
    *(us4v*)(wb + 6144)   = v3; \
  } while (0)

  f32x4 acc[4][2];
  #pragma unroll
  for (int i = 0; i < 4; ++i)
    #pragma unroll
    for (int j = 0; j < 2; ++j)
      #pragma unroll
      for (int q = 0; q < 4; ++q) acc[i][j][q] = 0.0f;

  int sa = rcol0 & 7;
  const char* aRd = lds + (wr * 64 + rcol0) * 128;          // + i*2048 + chunk*16 + buf*24576
  const char* bRd = lds + 16384 + (wc * 32 + rcol0) * 128;  // + j*2048 + chunk*16 + buf*24576

#define COMPUTE(buf) do { \
    const char* ra = aRd + (buf) * 24576; \
    const char* rb = bRd + (buf) * 24576; \
    _Pragma("unroll") for (int ks = 0; ks < 2; ++ks) { \
      int ch = (((ks * 4 + klane) ^ sa) << 4); \
      bf16x8 b0 = *(const bf16x8*)(rb + ch); \
      bf16x8 b1 = *(const bf16x8*)(rb + 2048 + ch); \
      bf16x8 a0 = *(const bf16x8*)(ra + ch); \
      bf16x8 a1 = *(const bf16x8*)(ra + 2048 + ch); \
      bf16x8 a2 = *(const bf16x8*)(ra + 4096 + ch); \
      bf16x8 a3 = *(const bf16x8*)(ra + 6144 + ch); \
      acc[0][0] = __builtin_amdgcn_mfma_f32_16x16x32_bf16(a0, b0, acc[0][0], 0, 0, 0); \
      acc[0][1] = __builtin_amdgcn_mfma_f32_16x16x32_bf16(a0, b1, acc[0][1], 0, 0, 0); \
      acc[1][0] = __builtin_amdgcn_mfma_f32_16x16x32_bf16(a1, b0, acc[1][0], 0, 0, 0); \
      acc[1][1] = __builtin_amdgcn_mfma_f32_16x16x32_bf16(a1, b1, acc[1][1], 0, 0, 0); \
      acc[2][0] = __builtin_amdgcn_mfma_f32_16x16x32_bf16(a2, b0, acc[2][0], 0, 0, 0); \
      acc[2][1] = __builtin_amdgcn_mfma_f32_16x16x32_bf16(a2, b1, acc[2][1], 0, 0, 0); \
      acc[3][0] = __builtin_amdgcn_mfma_f32_16x16x32_bf16(a3, b0, acc[3][0], 0, 0, 0); \
      acc[3][1] = __builtin_amdgcn_mfma_f32_16x16x32_bf16(a3, b1, acc[3][1], 0, 0, 0); \
    } \
  } while (0)

  // prologue: stage tile 0 into buf 0
  LOADB_G(0);
  STAGE_A(0, 0);
  WRITE_B(0);
  __syncthreads();

  for (int kt = 0; kt < 32; ++kt) {
    int cur = kt & 1;
    if (kt < 31) {
      LOADB_G(kt + 1);        // issue HBM loads early (hide under compute)
      STAGE_A(kt + 1, cur ^ 1);
    }
    COMPUTE(cur);
    if (kt < 31) WRITE_B(cur ^ 1);
    __syncthreads();
  }

#undef STAGE_A
#undef LOADB_G
#undef WRITE_B
#undef COMPUTE

  // fused epilogue: per-row partials over this block's 64-col span (this wave: 32 cols).
  // p1 = sum exp(20d-20), Z1 = sum exp(D-2), Z2 = sum exp(2(D-2)), Z3 = sum exp(3(D-2))
  // D = sqrt(max(2-2d,0)).  C/D layout: col = lane&15, row = klane*4 + q.
  int tbase = branch * 256;
  int mbase = mtile * 128;
  #pragma unroll
  for (int i = 0; i < 4; ++i) {
    #pragma unroll
    for (int q = 0; q < 4; ++q) {
      int row = mbase + wr * 64 + i * 16 + (klane << 2) + q;   // row in [0,256)
      int tgt = targets[row];
      float s1 = 0.f, s2 = 0.f, s3 = 0.f, s4 = 0.f;
      #pragma unroll
      for (int j = 0; j < 2; ++j) {
        float d = acc[i][j][q];
        float e1 = __expf(fmaf(20.0f, d, -20.0f));
        float Dv = sqrtf(fmaxf(2.0f - 2.0f * d, 0.0f));
        float e2 = __expf(Dv - 2.0f);
        s1 += e1; s2 += e2;
        float t2 = e2 * e2;
        s3 += t2; s4 += t2 * e2;
        int col = ntile * 64 + wc * 32 + j * 16 + rcol0;
        if (col == tgt) dotT[tbase + row] = d;   // exactly one writer per row globally
      }
      #pragma unroll
      for (int m = 1; m < 16; m <<= 1) {         // reduce across 16 lanes sharing this row
        s1 += __shfl_xor(s1, m);
        s2 += __shfl_xor(s2, m);
        s3 += __shfl_xor(s3, m);
        s4 += __shfl_xor(s4, m);
      }
      if (rcol0 == 0) {
        f32x4 p; p[0] = s1; p[1] = s2; p[2] = s3; p[3] = s4;
        *(f32x4*)(part + ((size_t)(tbase + row) * 256 + ntile * 2 + wc) * 4) = p;
      }
    }
  }
}

// ---------------- kernel 3: combine 256 tile-partials per row -> row loss ----------------
__global__ __launch_bounds__(256) void k_combine(
    const float* __restrict__ part, const float* __restrict__ dotT, float* __restrict__ rowloss)
{
  int row = blockIdx.x;    // 0..767
  int tid = threadIdx.x;   // 256
  f4v p = *(const f4v*)(part + ((size_t)row * 256 + tid) * 4);
  float a0 = p[0], a1 = p[1], a2 = p[2], a3 = p[3];
  #pragma unroll
  for (int m = 1; m < 64; m <<= 1) {
    a0 += __shfl_xor(a0, m); a1 += __shfl_xor(a1, m);
    a2 += __shfl_xor(a2, m); a3 += __shfl_xor(a3, m);
  }
  __shared__ float ls[4][4];
  if ((tid & 63) == 0) {
    int w = tid >> 6;
    ls[0][w] = a0; ls[1][w] = a1; ls[2][w] = a2; ls[3][w] = a3;
  }
  __syncthreads();
  if (tid == 0) {
    float p1 = ls[0][0] + ls[0][1] + ls[0][2] + ls[0][3];
    float Z1 = ls[1][0] + ls[1][1] + ls[1][2] + ls[1][3];
    float Z2 = ls[2][0] + ls[2][1] + ls[2][2] + ls[2][3];
    float Z3 = ls[3][0] + ls[3][1] + ls[3][2] + ls[3][3];
    float dt = dotT[row];
    // CE1 = logsumexp(20*dot) - 20*dot_t   (fixed shift 20 is exact: 20d-20 <= 0)
    float CE1 = 20.0f + logf(p1) - 20.0f * dt;
    // CE2 = log(sum_n exp(S_n)) - S_t ;  sum_n exp(S_n) = N + 1 + Z2/(2 Z1^2) + Z3/(6 Z1^3)
    float Dt = sqrtf(fmaxf(2.0f - 2.0f * dt, 0.0f));
    float St = __expf(Dt - 2.0f) / Z1;
    float sES = 8193.0f + Z2 / (2.0f * Z1 * Z1) + Z3 / (6.0f * Z1 * Z1 * Z1);
    float CE2 = logf(sES) - St;
    rowloss[row] = (CE1 + CE2) * (0.5f / 256.0f);
  }
}

// ---------------- kernel 4: final sum ----------------
__global__ __launch_bounds__(256) void k_final(const float* __restrict__ rowloss, float* __restrict__ out)
{
  int tid = threadIdx.x;
  float v = rowloss[tid] + rowloss[tid + 256] + rowloss[tid + 512];
  #pragma unroll
  for (int m = 1; m < 64; m <<= 1) v += __shfl_xor(v, m);
  __shared__ float ls[4];
  if ((tid & 63) == 0) ls[tid >> 6] = v;
  __syncthreads();
  if (tid == 0) out[0] = ls[0] + ls[1] + ls[2] + ls[3];
}

extern "C" void kernel_launch(void* const* d_in, const int* in_sizes, int n_in,
                              void* d_out, int out_size, void* d_ws, size_t ws_size,
                              hipStream_t stream) {
  const float* in0 = (const float*)d_in[0];
  const float* in1 = (const float*)d_in[1];
  const float* in2 = (const float*)d_in[2];
  const int* targets = (const int*)d_in[3];
  // d_in[4] = epoch (unused by the loss)
  const float* f0 = (const float*)d_in[5];
  const float* f1 = (const float*)d_in[6];
  const float* f2 = (const float*)d_in[7];

  char* ws = (char*)d_ws;
  unsigned short* xn = (unsigned short*)(ws + OFF_XN);
  float* part    = (float*)(ws + OFF_PART);
  float* dotT    = (float*)(ws + OFF_DOTT);
  float* rowloss = (float*)(ws + OFF_ROWLOSS);
  float* out = (float*)d_out;

  k_normalize<<<768, 256, 0, stream>>>(in0, in1, in2, xn);
  k_gemm_fused<<<768, 256, 0, stream>>>(xn, f0, f1, f2, targets, part, dotT);
  k_combine<<<768, 256, 0, stream>>>(part, dotT, rowloss);
  k_final<<<1, 256, 0, stream>>>(rowloss, out);
}

// Round 6
// 65.891 us; speedup vs baseline: 2.0216x; 1.0738x over previous
//
#include <hip/hip_runtime.h>

typedef float f4v __attribute__((ext_vector_type(4)));
typedef float f32x4 __attribute__((ext_vector_type(4)));
typedef __bf16 bf16x8 __attribute__((ext_vector_type(8)));
typedef __bf16 bf16x4 __attribute__((ext_vector_type(4)));
typedef unsigned short ushort8 __attribute__((ext_vector_type(8)));

static constexpr int KDIM = 2048;

// workspace layout (bytes)
static constexpr size_t OFF_XN      = 0;                                     // ushort [3][256][2048]  (3 MB)
static constexpr size_t OFF_PART    = (size_t)3 * 256 * 2048 * 2;            // float  [768][256][4]   (3 MB)
static constexpr size_t OFF_DOTT    = OFF_PART + (size_t)768 * 256 * 16;     // float  [768]
static constexpr size_t OFF_ROWLOSS = OFF_DOTT + 768 * 4;                    // float  [768]

__device__ __forceinline__ unsigned short f2bf(float x) {
  union { float f; unsigned u; } c; c.f = x;
  unsigned r = c.u + 0x7fffu + ((c.u >> 16) & 1u);   // RNE
  return (unsigned short)(r >> 16);
}

__device__ __forceinline__ void gload_lds16(const void* g, void* l) {
  __builtin_amdgcn_global_load_lds((const __attribute__((address_space(1))) void*)g,
                                   (__attribute__((address_space(3))) void*)l,
                                   16, 0, 0);
}

// f32x4 -> bf16x4 (compiler emits v_cvt_pk_bf16_f32 pairs) -> 8B LDS store
__device__ __forceinline__ void cvt_store8(char* p, f4v v) {
  bf16x4 o;
  o[0] = (__bf16)v[0]; o[1] = (__bf16)v[1]; o[2] = (__bf16)v[2]; o[3] = (__bf16)v[3];
  *(bf16x4*)p = o;
}

// ---------------- kernel 1: row-normalize inputs -> bf16 ----------------
__global__ __launch_bounds__(256) void k_normalize(
    const float* __restrict__ x0, const float* __restrict__ x1, const float* __restrict__ x2,
    unsigned short* __restrict__ xn)
{
  int bid = blockIdx.x;            // 0..767 : branch*256 + row
  int branch = bid >> 8;
  int row = bid & 255;
  const float* src = (branch == 0 ? x0 : (branch == 1 ? x1 : x2)) + (size_t)row * KDIM;
  int tid = threadIdx.x;
  f4v a = *(const f4v*)(src + tid * 8);
  f4v b = *(const f4v*)(src + tid * 8 + 4);
  float s = a[0]*a[0] + a[1]*a[1] + a[2]*a[2] + a[3]*a[3]
          + b[0]*b[0] + b[1]*b[1] + b[2]*b[2] + b[3]*b[3];
  #pragma unroll
  for (int m = 1; m < 64; m <<= 1) s += __shfl_xor(s, m);
  __shared__ float ls[4];
  if ((tid & 63) == 0) ls[tid >> 6] = s;
  __syncthreads();
  float total = ls[0] + ls[1] + ls[2] + ls[3];
  float inv = 1.0f / fmaxf(sqrtf(total), 1e-12f);
  ushort8 u;
  #pragma unroll
  for (int e = 0; e < 4; ++e) u[e]     = f2bf(a[e] * inv);
  #pragma unroll
  for (int e = 0; e < 4; ++e) u[4 + e] = f2bf(b[e] * inv);
  *(ushort8*)(xn + (size_t)bid * KDIM + tid * 8) = u;
}

// ---------------- kernel 2: fused GEMM + per-tile reductions ----------------
// BM=128, BN=64, BK=64. Grid = 768 = 3 blocks/CU. 4 waves (2M x 2N), each 64x32.
// A (bf16 xn): global_load_lds (dbuf), staged 1 tile ahead.
// B (f32 features): global->reg 2 tiles ahead -> cvt_pk bf16 -> swizzled ds_write (dbuf).
// Raw s_barrier + counted vmcnt: B loads stay in flight across barriers (T4).
// Issue order per phase: STAGE_A first, then LOADB -> vmcnt(4) retires A, leaves B flying.
__global__ __launch_bounds__(256, 3) void k_gemm_fused(
    const unsigned short* __restrict__ xn,
    const float* __restrict__ f0, const float* __restrict__ f1, const float* __restrict__ f2,
    const int* __restrict__ targets,
    float* __restrict__ part, float* __restrict__ dotT)
{
  // per buffer: A = 128 rows x 128B = 16 KiB, B = 64 cols x 128B = 8 KiB
  __shared__ char lds[2 * 24576];

  int bid = blockIdx.x;
  int swz = (bid & 7) * 96 + (bid >> 3);   // XCD-aware, 768 % 8 == 0 -> bijective
  int branch = swz >> 8;
  int ntile = (swz & 255) >> 1;            // 128 n-tiles of 64 cols
  int mtile = swz & 1;                     // 2 m-tiles of 128 rows (siblings share B via L2/L3)

  const unsigned short* A = xn + ((size_t)branch * 256 + (size_t)mtile * 128) * KDIM;
  const float* F = (branch == 0 ? f0 : (branch == 1 ? f1 : f2)) + (size_t)ntile * 64 * KDIM;

  int tid = threadIdx.x;
  int wave = tid >> 6;
  int lane = tid & 63;
  int rcol0 = lane & 15;
  int klane = lane >> 4;
  int wr = wave >> 1;    // M quadrant (0..1)
  int wc = wave & 1;     // N quadrant (0..1)

  // ---- A staging: 4 x gload_lds(16B) per thread, source pre-swizzled, linear LDS dest.
  const unsigned short* aSrc = A + (size_t)(tid >> 3) * KDIM
                             + (((tid & 7) ^ ((tid >> 3) & 7)) << 3);
  char* aDst = lds + (wave * 64) * 16;

#define STAGE_A(kt, buf) do { \
    _Pragma("unroll") for (int g = 0; g < 4; ++g) \
      gload_lds16(aSrc + (size_t)g * 32 * KDIM + (kt) * 64, \
                  aDst + (buf) * 24576 + g * 4096); \
  } while (0)

  // ---- B global loads: row = g*16 + (tid>>4), 16B chunk = tid&15.
  const float* bSrc = F + (size_t)(tid >> 4) * KDIM + (tid & 15) * 4;

#define LOADB_G(kt, r0, r1, r2, r3) do { \
    r0 = *(const f4v*)(bSrc + (kt) * 64); \
    r1 = *(const f4v*)(bSrc + 16 * KDIM + (kt) * 64); \
    r2 = *(const f4v*)(bSrc + 32 * KDIM + (kt) * 64); \
    r3 = *(const f4v*)(bSrc + 48 * KDIM + (kt) * 64); \
  } while (0)

  // ---- B LDS write addressing (same swizzle as round 5; bank-conflict-free measured)
  int bOff = 16384 + (tid >> 4) * 128
           + (((((tid & 15) >> 1)) ^ ((tid >> 4) & 7)) << 4) + (tid & 1) * 8;

#define WRITE_B(r0, r1, r2, r3, buf) do { \
    char* wb = lds + (buf) * 24576 + bOff; \
    cvt_store8(wb,         r0); \
    cvt_store8(wb + 2048,  r1); \
    cvt_store8(wb + 4096,  r2); \
    cvt_store8(wb + 6144,  r3); \
  } while (0)

  f32x4 acc[4][2];
  #pragma unroll
  for (int i = 0; i < 4; ++i)
    #pragma unroll
    for (int j = 0; j < 2; ++j)
      #pragma unroll
      for (int q = 0; q < 4; ++q) acc[i][j][q] = 0.0f;

  int sa = rcol0 & 7;
  const char* aRd = lds + (wr * 64 + rcol0) * 128;
  const char* bRd = lds + 16384 + (wc * 32 + rcol0) * 128;

#define COMPUTE(buf) do { \
    const char* ra = aRd + (buf) * 24576; \
    const char* rb = bRd + (buf) * 24576; \
    _Pragma("unroll") for (int ks = 0; ks < 2; ++ks) { \
      int ch = (((ks * 4 + klane) ^ sa) << 4); \
      bf16x8 b0 = *(const bf16x8*)(rb + ch); \
      bf16x8 b1 = *(const bf16x8*)(rb + 2048 + ch); \
      bf16x8 a0 = *(const bf16x8*)(ra + ch); \
      bf16x8 a1 = *(const bf16x8*)(ra + 2048 + ch); \
      bf16x8 a2 = *(const bf16x8*)(ra + 4096 + ch); \
      bf16x8 a3 = *(const bf16x8*)(ra + 6144 + ch); \
      acc[0][0] = __builtin_amdgcn_mfma_f32_16x16x32_bf16(a0, b0, acc[0][0], 0, 0, 0); \
      acc[0][1] = __builtin_amdgcn_mfma_f32_16x16x32_bf16(a0, b1, acc[0][1], 0, 0, 0); \
      acc[1][0] = __builtin_amdgcn_mfma_f32_16x16x32_bf16(a1, b0, acc[1][0], 0, 0, 0); \
      acc[1][1] = __builtin_amdgcn_mfma_f32_16x16x32_bf16(a1, b1, acc[1][1], 0, 0, 0); \
      acc[2][0] = __builtin_amdgcn_mfma_f32_16x16x32_bf16(a2, b0, acc[2][0], 0, 0, 0); \
      acc[2][1] = __builtin_amdgcn_mfma_f32_16x16x32_bf16(a2, b1, acc[2][1], 0, 0, 0); \
      acc[3][0] = __builtin_amdgcn_mfma_f32_16x16x32_bf16(a3, b0, acc[3][0], 0, 0, 0); \
      acc[3][1] = __builtin_amdgcn_mfma_f32_16x16x32_bf16(a3, b1, acc[3][1], 0, 0, 0); \
    } \
  } while (0)

  // counted drain: A of this phase retired, 4 B-loads left flying across the barrier
#define PHASE_END_4() do { \
    asm volatile("s_waitcnt vmcnt(4) lgkmcnt(0)" ::: "memory"); \
    __builtin_amdgcn_s_barrier(); \
    __builtin_amdgcn_sched_barrier(0); \
  } while (0)

  f4v pA0, pA1, pA2, pA3;   // B-tile ping
  f4v pB0, pB1, pB2, pB3;   // B-tile pong

  // prologue: A0 staged; B0, B1 issued; B0 written (auto-wait retires A0+B0, B1 flies)
  STAGE_A(0, 0);
  __builtin_amdgcn_sched_barrier(0);
  LOADB_G(0, pA0, pA1, pA2, pA3);
  LOADB_G(1, pB0, pB1, pB2, pB3);
  WRITE_B(pA0, pA1, pA2, pA3, 0);
  PHASE_END_4();

  for (int t = 0; t < 30; t += 2) {
    // phase t (even): stage A(t+1)->buf1, load B(t+2)->ping, write B(t+1)=pong->buf1, compute tile t
    STAGE_A(t + 1, 1);
    __builtin_amdgcn_sched_barrier(0);
    LOADB_G(t + 2, pA0, pA1, pA2, pA3);
    WRITE_B(pB0, pB1, pB2, pB3, 1);
    COMPUTE(0);
    PHASE_END_4();
    // phase t+1 (odd): stage A(t+2)->buf0, load B(t+3)->pong, write B(t+2)=ping->buf0, compute t+1
    STAGE_A(t + 2, 0);
    __builtin_amdgcn_sched_barrier(0);
    LOADB_G(t + 3, pB0, pB1, pB2, pB3);
    WRITE_B(pA0, pA1, pA2, pA3, 0);
    COMPUTE(1);
    PHASE_END_4();
  }
  // phase 30: stage A(31)->buf1, write B(31)=pong->buf1, compute tile 30; full drain
  STAGE_A(31, 1);
  WRITE_B(pB0, pB1, pB2, pB3, 1);
  COMPUTE(0);
  asm volatile("s_waitcnt vmcnt(0) lgkmcnt(0)" ::: "memory");
  __builtin_amdgcn_s_barrier();
  __builtin_amdgcn_sched_barrier(0);
  // phase 31
  COMPUTE(1);

#undef STAGE_A
#undef LOADB_G
#undef WRITE_B
#undef COMPUTE
#undef PHASE_END_4

  // fused epilogue: per-row partials over this wave's 32-col span.
  // p1 = sum exp(20d-20), Z1 = sum exp(D-2), Z2 = sum exp(2(D-2)), Z3 = sum exp(3(D-2))
  // D = sqrt(max(2-2d,0)).  C/D layout: col = lane&15, row = klane*4 + q.
  int tbase = branch * 256;
  int mbase = mtile * 128;
  #pragma unroll
  for (int i = 0; i < 4; ++i) {
    #pragma unroll
    for (int q = 0; q < 4; ++q) {
      int row = mbase + wr * 64 + i * 16 + (klane << 2) + q;   // row in [0,256)
      int tgt = targets[row];
      float s1 = 0.f, s2 = 0.f, s3 = 0.f, s4 = 0.f;
      #pragma unroll
      for (int j = 0; j < 2; ++j) {
        float d = acc[i][j][q];
        float e1 = __expf(fmaf(20.0f, d, -20.0f));
        float Dv = sqrtf(fmaxf(2.0f - 2.0f * d, 0.0f));
        float e2 = __expf(Dv - 2.0f);
        s1 += e1; s2 += e2;
        float t2 = e2 * e2;
        s3 += t2; s4 += t2 * e2;
        int col = ntile * 64 + wc * 32 + j * 16 + rcol0;
        if (col == tgt) dotT[tbase + row] = d;   // exactly one writer per row globally
      }
      #pragma unroll
      for (int m = 1; m < 16; m <<= 1) {         // reduce across 16 lanes sharing this row
        s1 += __shfl_xor(s1, m);
        s2 += __shfl_xor(s2, m);
        s3 += __shfl_xor(s3, m);
        s4 += __shfl_xor(s4, m);
      }
      if (rcol0 == 0) {
        f32x4 p; p[0] = s1; p[1] = s2; p[2] = s3; p[3] = s4;
        *(f32x4*)(part + ((size_t)(tbase + row) * 256 + ntile * 2 + wc) * 4) = p;
      }
    }
  }
}

// ---------------- kernel 3: combine 256 tile-partials per row -> row loss ----------------
__global__ __launch_bounds__(256) void k_combine(
    const float* __restrict__ part, const float* __restrict__ dotT, float* __restrict__ rowloss)
{
  int row = blockIdx.x;    // 0..767
  int tid = threadIdx.x;   // 256
  f4v p = *(const f4v*)(part + ((size_t)row * 256 + tid) * 4);
  float a0 = p[0], a1 = p[1], a2 = p[2], a3 = p[3];
  #pragma unroll
  for (int m = 1; m < 64; m <<= 1) {
    a0 += __shfl_xor(a0, m); a1 += __shfl_xor(a1, m);
    a2 += __shfl_xor(a2, m); a3 += __shfl_xor(a3, m);
  }
  __shared__ float ls[4][4];
  if ((tid & 63) == 0) {
    int w = tid >> 6;
    ls[0][w] = a0; ls[1][w] = a1; ls[2][w] = a2; ls[3][w] = a3;
  }
  __syncthreads();
  if (tid == 0) {
    float p1 = ls[0][0] + ls[0][1] + ls[0][2] + ls[0][3];
    float Z1 = ls[1][0] + ls[1][1] + ls[1][2] + ls[1][3];
    float Z2 = ls[2][0] + ls[2][1] + ls[2][2] + ls[2][3];
    float Z3 = ls[3][0] + ls[3][1] + ls[3][2] + ls[3][3];
    float dt = dotT[row];
    // CE1 = logsumexp(20*dot) - 20*dot_t   (fixed shift 20 is exact: 20d-20 <= 0)
    float CE1 = 20.0f + logf(p1) - 20.0f * dt;
    // CE2 = log(sum_n exp(S_n)) - S_t ;  sum_n exp(S_n) = N + 1 + Z2/(2 Z1^2) + Z3/(6 Z1^3)
    float Dt = sqrtf(fmaxf(2.0f - 2.0f * dt, 0.0f));
    float St = __expf(Dt - 2.0f) / Z1;
    float sES = 8193.0f + Z2 / (2.0f * Z1 * Z1) + Z3 / (6.0f * Z1 * Z1 * Z1);
    float CE2 = logf(sES) - St;
    rowloss[row] = (CE1 + CE2) * (0.5f / 256.0f);
  }
}

// ---------------- kernel 4: final sum ----------------
__global__ __launch_bounds__(256) void k_final(const float* __restrict__ rowloss, float* __restrict__ out)
{
  int tid = threadIdx.x;
  float v = rowloss[tid] + rowloss[tid + 256] + rowloss[tid + 512];
  #pragma unroll
  for (int m = 1; m < 64; m <<= 1) v += __shfl_xor(v, m);
  __shared__ float ls[4];
  if ((tid & 63) == 0) ls[tid >> 6] = v;
  __syncthreads();
  if (tid == 0) out[0] = ls[0] + ls[1] + ls[2] + ls[3];
}

extern "C" void kernel_launch(void* const* d_in, const int* in_sizes, int n_in,
                              void* d_out, int out_size, void* d_ws, size_t ws_size,
                              hipStream_t stream) {
  const float* in0 = (const float*)d_in[0];
  const float* in1 = (const float*)d_in[1];
  const float* in2 = (const float*)d_in[2];
  const int* targets = (const int*)d_in[3];
  // d_in[4] = epoch (unused by the loss)
  const float* f0 = (const float*)d_in[5];
  const float* f1 = (const float*)d_in[6];
  const float* f2 = (const float*)d_in[7];

  char* ws = (char*)d_ws;
  unsigned short* xn = (unsigned short*)(ws + OFF_XN);
  float* part    = (float*)(ws + OFF_PART);
  float* dotT    = (float*)(ws + OFF_DOTT);
  float* rowloss = (float*)(ws + OFF_ROWLOSS);
  float* out = (float*)d_out;

  k_normalize<<<768, 256, 0, stream>>>(in0, in1, in2, xn);
  k_gemm_fused<<<768, 256, 0, stream>>>(xn, f0, f1, f2, targets, part, dotT);
  k_combine<<<768, 256, 0, stream>>>(part, dotT, rowloss);
  k_final<<<1, 256, 0, stream>>>(rowloss, out);
}